// Round 1
// baseline (2642.471 us; speedup 1.0000x reference)
//
#include <hip/hip_runtime.h>
#include <hip/hip_fp16.h>
#include <stdint.h>

// ClockworkRNN MI355X round 1.
// Design: (1) cvt X->f16, W->W^T f16; (2) per-module compact x-projection GEMM
// (f16 MFMA 16x16x32, only timesteps where the module updates); (3) persistent
// scan: 1 workgroup (1024 thr) per batch element, weights register/LDS-resident
// as f16 pairs, v_dot2_f32_f16 inner product, fp32 h-shadow for tanh chains.
// ws layout (bytes): [0, 67108864) X f16 | [67108864, 67371008) W^T f16 |
//                    [67371008, 100794368) compact x f16.

typedef _Float16 half_t;
typedef _Float16 h2 __attribute__((ext_vector_type(2)));
typedef _Float16 h8 __attribute__((ext_vector_type(8)));
typedef float f4 __attribute__((ext_vector_type(4)));

__device__ __forceinline__ float dot2f(h2 a, h2 b, float c) {
#if defined(__has_builtin)
#if __has_builtin(__builtin_amdgcn_fdot2)
  return __builtin_amdgcn_fdot2(a, b, c, false);
#else
  return c + (float)a[0] * (float)b[0] + (float)a[1] * (float)b[1];
#endif
#else
  return c + (float)a[0] * (float)b[0] + (float)a[1] * (float)b[1];
#endif
}

__device__ __forceinline__ void gl_lds16(const half_t* g, half_t* l) {
  __builtin_amdgcn_global_load_lds(
      (__attribute__((address_space(1))) void*)(void*)g,
      (__attribute__((address_space(3))) void*)(void*)l, 16, 0, 0);
}

// ---------------- cvt kernels ----------------
__global__ void cw_cvt_x(const float* __restrict__ X, half_t* __restrict__ Xh, long n4) {
  long i = (long)blockIdx.x * blockDim.x + threadIdx.x;
  const long stride = (long)gridDim.x * blockDim.x;
  const float4* X4 = (const float4*)X;
  h2* out2 = (h2*)Xh;
  for (; i < n4; i += stride) {
    float4 v = X4[i];
    h2 a; a[0] = (half_t)v.x; a[1] = (half_t)v.y;
    h2 b; b[0] = (half_t)v.z; b[1] = (half_t)v.w;
    out2[2 * i] = a;
    out2[2 * i + 1] = b;
  }
}

__global__ void cw_cvt_wt(const float* __restrict__ W, half_t* __restrict__ WT) {
  int idx = blockIdx.x * 256 + threadIdx.x;  // 131072 total
  int o = idx >> 8, d = idx & 255;
  WT[idx] = (half_t)W[d * 512 + o];
}

// ---------------- x projection: compact per-module GEMM ----------------
// grid (512, 8): y = module, x = 256-row tile. A = Xh rows (b, t = k*2^mod),
// B = WT rows [mod*64, mod*64+64) (n-major [n][k]). Out: compact f16.
__global__ __launch_bounds__(256) void cw_xproj(const half_t* __restrict__ Xh,
                                                const half_t* __restrict__ WT,
                                                const float* __restrict__ bias,
                                                half_t* __restrict__ xout) {
  const int mod = blockIdx.y;
  const int Ti = 2048 >> mod;
  const long Mi = (long)64 * Ti;
  const long m0r = (long)blockIdx.x * 256;
  if (m0r >= Mi) return;
  __shared__ alignas(16) half_t Bs[64 * 256];
  __shared__ alignas(16) half_t As[256 * 64];
  const int tid = threadIdx.x;
  const int wv = tid >> 6, l = tid & 63;
  const int lr = l & 15, lk = (l >> 4) * 8;
  const int shf = 11 - mod;

  // stage B once: 64 rows x 512B = 2048 16B-chunks
#pragma unroll
  for (int it = 0; it < 8; ++it) {
    int slot = it * 256 + tid;
    int n = slot >> 5, kc = slot & 31;
    gl_lds16(WT + ((mod << 6) + n) * 256 + kc * 8, Bs + slot * 8);
  }

  f4 acc[4][4];
#pragma unroll
  for (int a = 0; a < 4; ++a)
#pragma unroll
    for (int bq = 0; bq < 4; ++bq) acc[a][bq] = f4{0.f, 0.f, 0.f, 0.f};

  for (int kt = 0; kt < 4; ++kt) {
#pragma unroll
    for (int it = 0; it < 8; ++it) {
      int slot = it * 256 + tid;
      int r = slot >> 3, kc = slot & 7;
      long m = m0r + r;
      long g = (m >> shf) * 2048 + ((m & (long)(Ti - 1)) << mod);
      gl_lds16(Xh + g * 256 + kt * 64 + kc * 8, As + slot * 8);
    }
    __syncthreads();
#pragma unroll
    for (int ks = 0; ks < 2; ++ks) {
      h8 af[4], bf[4];
#pragma unroll
      for (int mi = 0; mi < 4; ++mi)
        af[mi] = *(const h8*)&As[(wv * 64 + mi * 16 + lr) * 64 + ks * 32 + lk];
#pragma unroll
      for (int ni = 0; ni < 4; ++ni)
        bf[ni] = *(const h8*)&Bs[(ni * 16 + lr) * 256 + kt * 64 + ks * 32 + lk];
#pragma unroll
      for (int mi = 0; mi < 4; ++mi)
#pragma unroll
        for (int ni = 0; ni < 4; ++ni)
          acc[mi][ni] = __builtin_amdgcn_mfma_f32_16x16x32_f16(af[mi], bf[ni], acc[mi][ni], 0, 0, 0);
    }
    __syncthreads();
  }

  const long xb = 16777216L - (16777216L >> mod);
#pragma unroll
  for (int ni = 0; ni < 4; ++ni) {
    int n = ni * 16 + lr;
    float bv = bias[(mod << 6) + n];
#pragma unroll
    for (int mi = 0; mi < 4; ++mi) {
      f4 cf = acc[mi][ni];
#pragma unroll
      for (int q = 0; q < 4; ++q) {
        long m = m0r + wv * 64 + mi * 16 + (l >> 4) * 4 + q;
        xout[xb + m * 64 + n] = (half_t)(cf[q] + bv);
      }
    }
  }
}

// ---------------- persistent scan: 1 WG per batch ----------------
// 1024 threads. Fast roles (every thread): tid<512 -> m0 (8 splits of 64),
// tid>=512 -> m1 (8 splits of 64, last padded w/ zeros; h pad [512,576)=0).
// Slow roles: tid>>8 == 0:m2(reg,4x96) 1:m3(reg,4x80) 2:m4(reg,4x64)
//             3: m5(LDS,4x48) + m6(LDS,2x64 on waves 12-13) + m7(LDS,2x32 on 14-15).
__global__ __launch_bounds__(1024, 4) void cw_scan(
    const half_t* __restrict__ xbuf,
    const float* __restrict__ Wc0, const float* __restrict__ Wc1,
    const float* __restrict__ Wc2, const float* __restrict__ Wc3,
    const float* __restrict__ Wc4, const float* __restrict__ Wc5,
    const float* __restrict__ Wc6, const float* __restrict__ Wc7,
    float* __restrict__ out) {
  const int b = blockIdx.x;
  const int tid = threadIdx.x;
  const int c = tid & 63;
  const int wv = tid >> 6;
  const int fr = tid >> 9;     // fast role: 0=m0 1=m1
  const int j = wv & 7;        // fast split
  const int sr = tid >> 8;     // slow role selector
  const int jj = wv & 3;       // split for m2..m5

  __shared__ alignas(16) half_t hlds[640];  // h f16 [0,512) + zero pad [512,640)
  __shared__ float parts[2304];
  __shared__ h2 w567[12288];  // m5 [0,6144) m6 [6144,10240) m7 [10240,12288)

  // ---- weight init (one-time) ----
  h2 wfast[32];
  {
    const float* Wf = fr ? Wc1 : Wc0;
    const int rb = j << 6;
#pragma unroll
    for (int p = 0; p < 32; ++p) {
      int r = rb + 2 * p;
      float w0 = 0.f, w1 = 0.f;
      if (fr == 0) {
        w0 = Wf[r * 64 + c];
        w1 = Wf[(r + 1) * 64 + c];
      } else {
        if (r < 448) w0 = Wf[r * 64 + c];
        if (r + 1 < 448) w1 = Wf[(r + 1) * 64 + c];
      }
      h2 t2; t2[0] = (half_t)w0; t2[1] = (half_t)w1;
      wfast[p] = t2;
    }
  }
  h2 wslow[48];
  if (sr == 0) {
    const int rb = 96 * jj;
#pragma unroll
    for (int p = 0; p < 48; ++p) {
      int r = rb + 2 * p;
      h2 t2; t2[0] = (half_t)Wc2[r * 64 + c]; t2[1] = (half_t)Wc2[(r + 1) * 64 + c];
      wslow[p] = t2;
    }
  } else if (sr == 1) {
    const int rb = 80 * jj;
#pragma unroll
    for (int p = 0; p < 40; ++p) {
      int r = rb + 2 * p;
      h2 t2; t2[0] = (half_t)Wc3[r * 64 + c]; t2[1] = (half_t)Wc3[(r + 1) * 64 + c];
      wslow[p] = t2;
    }
  } else if (sr == 2) {
    const int rb = 64 * jj;
#pragma unroll
    for (int p = 0; p < 32; ++p) {
      int r = rb + 2 * p;
      h2 t2; t2[0] = (half_t)Wc4[r * 64 + c]; t2[1] = (half_t)Wc4[(r + 1) * 64 + c];
      wslow[p] = t2;
    }
  } else {
    const int rb = 48 * jj;  // m5 -> LDS
#pragma unroll
    for (int p = 0; p < 24; ++p) {
      int r = rb + 2 * p;
      h2 t2; t2[0] = (half_t)Wc5[r * 64 + c]; t2[1] = (half_t)Wc5[(r + 1) * 64 + c];
      w567[(jj * 24 + p) * 64 + c] = t2;
    }
    if (wv < 14) {  // m6 -> LDS (waves 12,13)
      const int j6 = wv - 12, rb6 = 64 * j6;
#pragma unroll
      for (int p = 0; p < 32; ++p) {
        int r = rb6 + 2 * p;
        h2 t2; t2[0] = (half_t)Wc6[r * 64 + c]; t2[1] = (half_t)Wc6[(r + 1) * 64 + c];
        w567[6144 + (j6 * 32 + p) * 64 + c] = t2;
      }
    } else {  // m7 -> LDS (waves 14,15)
      const int j7 = wv - 14, rb7 = 32 * j7;
#pragma unroll
      for (int p = 0; p < 16; ++p) {
        int r = rb7 + 2 * p;
        h2 t2; t2[0] = (half_t)Wc7[r * 64 + c]; t2[1] = (half_t)Wc7[(r + 1) * 64 + c];
        w567[10240 + (j7 * 16 + p) * 64 + c] = t2;
      }
    }
  }
  if (tid < 640) hlds[tid] = (half_t)0.f;

  float hs = 0.f, xn = 0.f;
  const int mi = tid >> 6;  // owner module (valid for tid<512)
  if (tid < 512) {
    long xb = 16777216L - (16777216L >> mi);
    xn = (float)xbuf[xb + ((long)b << (11 - mi)) * 64 + c];  // t=0 value
  }
  __syncthreads();

  for (int t = 0; t < 2048; ++t) {
    // ---- dot phase ----
    if (fr == 0 || (t & 1) == 0) {
      const h2* hp = (const h2*)__builtin_assume_aligned((const void*)&hlds[(j + fr) << 6], 16);
      float a0 = 0.f, a1 = 0.f, a2 = 0.f, a3 = 0.f;
#pragma unroll
      for (int p = 0; p < 32; p += 4) {
        a0 = dot2f(hp[p], wfast[p], a0);
        a1 = dot2f(hp[p + 1], wfast[p + 1], a1);
        a2 = dot2f(hp[p + 2], wfast[p + 2], a2);
        a3 = dot2f(hp[p + 3], wfast[p + 3], a3);
      }
      parts[(fr << 9) + (j << 6) + c] = (a0 + a1) + (a2 + a3);
    }
    if (sr == 0) {
      if ((t & 3) == 0) {
        const h2* hp = (const h2*)__builtin_assume_aligned((const void*)&hlds[128 + 96 * jj], 16);
        float a0 = 0.f, a1 = 0.f, a2 = 0.f, a3 = 0.f;
#pragma unroll
        for (int p = 0; p < 48; p += 4) {
          a0 = dot2f(hp[p], wslow[p], a0);
          a1 = dot2f(hp[p + 1], wslow[p + 1], a1);
          a2 = dot2f(hp[p + 2], wslow[p + 2], a2);
          a3 = dot2f(hp[p + 3], wslow[p + 3], a3);
        }
        parts[1024 + (jj << 6) + c] = (a0 + a1) + (a2 + a3);
      }
    } else if (sr == 1) {
      if ((t & 7) == 0) {
        const h2* hp = (const h2*)__builtin_assume_aligned((const void*)&hlds[192 + 80 * jj], 16);
        float a0 = 0.f, a1 = 0.f, a2 = 0.f, a3 = 0.f;
#pragma unroll
        for (int p = 0; p < 40; p += 4) {
          a0 = dot2f(hp[p], wslow[p], a0);
          a1 = dot2f(hp[p + 1], wslow[p + 1], a1);
          a2 = dot2f(hp[p + 2], wslow[p + 2], a2);
          a3 = dot2f(hp[p + 3], wslow[p + 3], a3);
        }
        parts[1280 + (jj << 6) + c] = (a0 + a1) + (a2 + a3);
      }
    } else if (sr == 2) {
      if ((t & 15) == 0) {
        const h2* hp = (const h2*)__builtin_assume_aligned((const void*)&hlds[256 + 64 * jj], 16);
        float a0 = 0.f, a1 = 0.f, a2 = 0.f, a3 = 0.f;
#pragma unroll
        for (int p = 0; p < 32; p += 4) {
          a0 = dot2f(hp[p], wslow[p], a0);
          a1 = dot2f(hp[p + 1], wslow[p + 1], a1);
          a2 = dot2f(hp[p + 2], wslow[p + 2], a2);
          a3 = dot2f(hp[p + 3], wslow[p + 3], a3);
        }
        parts[1536 + (jj << 6) + c] = (a0 + a1) + (a2 + a3);
      }
    } else {
      if ((t & 31) == 0) {
        const h2* hp = (const h2*)__builtin_assume_aligned((const void*)&hlds[320 + 48 * jj], 16);
        const h2* wp = &w567[jj * 1536 + c];
        float a0 = 0.f, a1 = 0.f, a2 = 0.f, a3 = 0.f;
#pragma unroll
        for (int p = 0; p < 24; p += 4) {
          a0 = dot2f(hp[p], wp[p * 64], a0);
          a1 = dot2f(hp[p + 1], wp[(p + 1) * 64], a1);
          a2 = dot2f(hp[p + 2], wp[(p + 2) * 64], a2);
          a3 = dot2f(hp[p + 3], wp[(p + 3) * 64], a3);
        }
        parts[1792 + (jj << 6) + c] = (a0 + a1) + (a2 + a3);
      }
      if ((t & 63) == 0 && wv < 14) {
        const int j6 = wv - 12;
        const h2* hp = (const h2*)__builtin_assume_aligned((const void*)&hlds[384 + 64 * j6], 16);
        const h2* wp = &w567[6144 + j6 * 2048 + c];
        float a0 = 0.f, a1 = 0.f, a2 = 0.f, a3 = 0.f;
#pragma unroll
        for (int p = 0; p < 32; p += 4) {
          a0 = dot2f(hp[p], wp[p * 64], a0);
          a1 = dot2f(hp[p + 1], wp[(p + 1) * 64], a1);
          a2 = dot2f(hp[p + 2], wp[(p + 2) * 64], a2);
          a3 = dot2f(hp[p + 3], wp[(p + 3) * 64], a3);
        }
        parts[2048 + (j6 << 6) + c] = (a0 + a1) + (a2 + a3);
      }
      if ((t & 127) == 0 && wv >= 14) {
        const int j7 = wv - 14;
        const h2* hp = (const h2*)__builtin_assume_aligned((const void*)&hlds[448 + 32 * j7], 16);
        const h2* wp = &w567[10240 + j7 * 1024 + c];
        float a0 = 0.f, a1 = 0.f, a2 = 0.f, a3 = 0.f;
#pragma unroll
        for (int p = 0; p < 16; p += 4) {
          a0 = dot2f(hp[p], wp[p * 64], a0);
          a1 = dot2f(hp[p + 1], wp[(p + 1) * 64], a1);
          a2 = dot2f(hp[p + 2], wp[(p + 2) * 64], a2);
          a3 = dot2f(hp[p + 3], wp[(p + 3) * 64], a3);
        }
        parts[2176 + (j7 << 6) + c] = (a0 + a1) + (a2 + a3);
      }
    }
    __syncthreads();
    // ---- owner phase ----
    if (tid < 512) {
      const int pm = (1 << mi) - 1;
      float hv;
      if ((t & pm) == 0) {
        int base, ns;
        if (mi < 2) { base = mi << 9; ns = 8; }
        else if (mi < 6) { base = 1024 + ((mi - 2) << 8); ns = 4; }
        else { base = 2048 + ((mi - 6) << 7); ns = 2; }
        float s = 0.f;
        for (int q = 0; q < ns; ++q) s += parts[base + (q << 6) + c];
        hv = tanhf(s + xn);
      } else {
        hv = tanhf(hs);
      }
      hs = hv;
      hlds[tid] = (half_t)hv;
      const int tn = t + 1;
      if (tn < 2048 && (tn & pm) == 0) {
        long xb = 16777216L - (16777216L >> mi);
        xn = (float)xbuf[xb + (((long)b << (11 - mi)) + (tn >> mi)) * 64 + c];
      }
    }
    __syncthreads();
  }
  if (tid < 512) out[(b << 9) + tid] = hs;
}

// ---------------- launcher ----------------
extern "C" void kernel_launch(void* const* d_in, const int* in_sizes, int n_in,
                              void* d_out, int out_size, void* d_ws, size_t ws_size,
                              hipStream_t stream) {
  const float* X = (const float*)d_in[0];
  const float* W = (const float*)d_in[1];
  const float* bias = (const float*)d_in[2];
  const float* Wc0 = (const float*)d_in[3];
  const float* Wc1 = (const float*)d_in[4];
  const float* Wc2 = (const float*)d_in[5];
  const float* Wc3 = (const float*)d_in[6];
  const float* Wc4 = (const float*)d_in[7];
  const float* Wc5 = (const float*)d_in[8];
  const float* Wc6 = (const float*)d_in[9];
  const float* Wc7 = (const float*)d_in[10];
  float* out = (float*)d_out;

  half_t* Xh = (half_t*)d_ws;                              // 67,108,864 B
  half_t* WT = (half_t*)((char*)d_ws + 67108864);          //    262,144 B
  half_t* xbuf = (half_t*)((char*)d_ws + 67371008);        // 33,423,360 B
  // total ws needed: 100,794,368 B

  cw_cvt_x<<<4096, 256, 0, stream>>>(X, Xh, 8388608L);
  cw_cvt_wt<<<512, 256, 0, stream>>>(W, WT);
  dim3 g(512, 8);
  cw_xproj<<<g, 256, 0, stream>>>(Xh, WT, bias, xbuf);
  cw_scan<<<64, 1024, 0, stream>>>(xbuf, Wc0, Wc1, Wc2, Wc3, Wc4, Wc5, Wc6, Wc7, out);
}